// Round 1
// 1109.187 us; speedup vs baseline: 1.4050x; 1.4050x over previous
//
#include <hip/hip_runtime.h>

typedef unsigned short u16;
typedef unsigned int   u32;
typedef __bf16 bfx8 __attribute__((ext_vector_type(8)));
typedef float  f32x4 __attribute__((ext_vector_type(4)));

__device__ __forceinline__ float b2f(u16 v) {
    union { u32 u; float f; } c; c.u = ((u32)v) << 16; return c.f;
}
__device__ __forceinline__ u16 f2bf(float f) {
    union { float f; u32 u; } c; c.f = f;
    u32 u = c.u;
    return (u16)((u + 0x7fffu + ((u >> 16) & 1u)) >> 16);  // RNE
}

// ---------------------------------------------------------------------------
// Input dtype detection: bf16 normal data -> nearly all even u16 elements have
// a plausible bf16 exponent; f32 data -> even u16s are mantissa halves
// (uniform bits, ~19% plausible). flag=1 means inputs are f32.
// ---------------------------------------------------------------------------
__global__ void detect_dtype(const u16* __restrict__ x, int* __restrict__ flag)
{
    const int tid = threadIdx.x;
    int cnt = 0;
    for (int i = tid; i < 2048; i += 256) {
        const u16 v = x[2 * i];
        const int e = (v >> 7) & 0xFF;
        if ((v & 0x7fff) == 0 || (e >= 96 && e <= 144)) cnt++;
    }
#pragma unroll
    for (int off = 32; off > 0; off >>= 1) cnt += __shfl_xor(cnt, off);
    __shared__ int sred[4];
    if ((tid & 63) == 0) sred[tid >> 6] = cnt;
    __syncthreads();
    if (tid == 0) {
        const int total = sred[0] + sred[1] + sred[2] + sred[3];
        flag[0] = (total < 1024) ? 1 : 0;
    }
}

// Convert small vector to bf16 (copy if already bf16)
__global__ void to_bf16(const void* __restrict__ in, u16* __restrict__ out,
                        int n, const int* __restrict__ flag)
{
    const int i = blockIdx.x * 256 + threadIdx.x;
    if (i < n)
        out[i] = (*flag) ? f2bf(((const float*)in)[i]) : ((const u16*)in)[i];
}

// ---------------------------------------------------------------------------
// Batched GEMM: C[m][n] = sum_k A[m][k] * Bt[n][k]   (acc f32)
// A may be raw input (f32 or bf16, per aF32 flag); Bt always bf16.
// epi_mode: 1 = store; 2 = (acc+add1)*mul1; 3 = acc+bias+add1
// Store width: f32 if cF32 flag set, else bf16.
// ---------------------------------------------------------------------------
__global__ __launch_bounds__(256, 2)
void gemm_bt(const void* __restrict__ A, const u16* __restrict__ Bt,
             void* __restrict__ C,
             int M, int N, int K, int lda, int ldb, int ldc,
             long sAb, long sAh, long sBb, long sBh, long sCb, long sCh, int nh,
             int epi_mode, const u16* __restrict__ add1, long sAddB, long sAddH,
             int ldadd, const u16* __restrict__ mul1, const u16* __restrict__ bias,
             const int* __restrict__ aF32, const int* __restrict__ cF32)
{
    __shared__ __align__(16) u16 As[128 * 40];
    __shared__ __align__(16) u16 Bs[128 * 40];
    const bool af32 = aF32 && (*aF32 != 0);
    const bool cf32 = cF32 && (*cF32 != 0);
    const int z = blockIdx.z, zb = z / nh, zh = z - zb * nh;
    const long aoff = (long)zb * sAb + (long)zh * sAh;
    Bt += (long)zb * sBb + (long)zh * sBh;
    const long coff = (long)zb * sCb + (long)zh * sCh;
    const int m0 = blockIdx.x * 128, n0 = blockIdx.y * 128;
    const int tid = threadIdx.x, lane = tid & 63, wave = tid >> 6;
    const int wm = (wave >> 1) * 64, wn = (wave & 1) * 64;
    const int q = lane >> 4, l16 = lane & 15;
    const int rowL = tid >> 2, kcol = (tid & 3) * 8;

    f32x4 acc[4][4] = {};

    for (int k0 = 0; k0 < K; k0 += 32) {
#pragma unroll
        for (int p = 0; p < 2; ++p) {
            const int r = rowL + p * 64;
            uint4 va = {0, 0, 0, 0}, vb = {0, 0, 0, 0};
            if (m0 + r < M) {
                const long ai = aoff + (long)(m0 + r) * lda + k0 + kcol;
                if (af32) {
                    const float* Af = (const float*)A + ai;
                    float4 f0 = *(const float4*)Af;
                    float4 f1 = *(const float4*)(Af + 4);
                    u16* u = (u16*)&va;
                    u[0] = f2bf(f0.x); u[1] = f2bf(f0.y);
                    u[2] = f2bf(f0.z); u[3] = f2bf(f0.w);
                    u[4] = f2bf(f1.x); u[5] = f2bf(f1.y);
                    u[6] = f2bf(f1.z); u[7] = f2bf(f1.w);
                } else {
                    va = *(const uint4*)((const u16*)A + ai);
                }
            }
            if (n0 + r < N) vb = *(const uint4*)(Bt + (long)(n0 + r) * ldb + k0 + kcol);
            *(uint4*)(&As[r * 40 + kcol]) = va;
            *(uint4*)(&Bs[r * 40 + kcol]) = vb;
        }
        __syncthreads();
        bfx8 af[4], bfr[4];
#pragma unroll
        for (int t = 0; t < 4; ++t) {
            af[t]  = *(const bfx8*)(&As[(wm + t * 16 + l16) * 40 + q * 8]);
            bfr[t] = *(const bfx8*)(&Bs[(wn + t * 16 + l16) * 40 + q * 8]);
        }
#pragma unroll
        for (int i = 0; i < 4; ++i)
#pragma unroll
            for (int j = 0; j < 4; ++j)
                acc[i][j] = __builtin_amdgcn_mfma_f32_16x16x32_bf16(af[i], bfr[j], acc[i][j], 0, 0, 0);
        __syncthreads();
    }

#pragma unroll
    for (int i = 0; i < 4; ++i) {
#pragma unroll
        for (int j = 0; j < 4; ++j) {
#pragma unroll
            for (int r = 0; r < 4; ++r) {
                const int gm = m0 + wm + i * 16 + q * 4 + r;
                const int gn = n0 + wn + j * 16 + l16;
                if (gm < M && gn < N) {
                    float v = acc[i][j][r];
                    const long cidx = coff + (long)gm * ldc + gn;
                    if (epi_mode == 2) {
                        const long aidx = (long)zb * sAddB + (long)zh * sAddH + (long)gm * ldadd + gn;
                        v = (v + b2f(add1[aidx])) * b2f(mul1[aidx]);
                    } else if (epi_mode == 3) {
                        const long aidx = (long)gm * ldadd + gn;
                        v = v + b2f(bias[gn]) + b2f(add1[aidx]);
                    }
                    if (cf32) ((float*)C)[cidx] = v;
                    else      ((u16*)C)[cidx] = f2bf(v);
                }
            }
        }
    }
}

// ---------------------------------------------------------------------------
// AT-GEMM: C[i][j] = sum_n A[n][i] * B[n][j]  (contract rows; ws bf16 in, f32 out)
// LDS transpose staging uses stride 64 + XOR swizzle:
//   idx(i,k) = i*64 + (k ^ (((i&7) ^ ((i>>3)&7)) << 3))
// Same involution on the scalar u16 writes and the b128 fragment reads, so
// 16B alignment is preserved (XOR only touches k-bits 3..5) and the old
// 16-32-way bank conflict on staging writes becomes ~2-4-way.
// K-splitting is driven by the call site through the zb stride (sAb/sBb are
// n-offsets, sCb the f32 partial-buffer stride); consumers sum partials.
// ---------------------------------------------------------------------------
__global__ __launch_bounds__(256, 2)
void gemm_at(const u16* __restrict__ A, const u16* __restrict__ B,
             float* __restrict__ C,
             int M, int N, int K, int lda, int ldb, int ldc,
             long sAb, long sAh, long sBb, long sBh, long sCb, long sCh, int nh)
{
    __shared__ __align__(16) u16 At[128 * 64];
    __shared__ __align__(16) u16 Bl[128 * 64];
    const int z = blockIdx.z, zb = z / nh, zh = z - zb * nh;
    A += (long)zb * sAb + (long)zh * sAh;
    B += (long)zb * sBb + (long)zh * sBh;
    const long coff = (long)zb * sCb + (long)zh * sCh;
    const int i0 = blockIdx.x * 128, j0 = blockIdx.y * 128;
    const int tid = threadIdx.x, lane = tid & 63, wave = tid >> 6;
    const int wm = (wave >> 1) * 64, wn = (wave & 1) * 64;
    const int q = lane >> 4, l16 = lane & 15;
    const int tr = tid >> 4, tc8 = (tid & 15) * 8;
    const int sw = (tc8 >> 3) & 7;

    f32x4 acc[4][4] = {};

    for (int n0 = 0; n0 < K; n0 += 64) {
#pragma unroll
        for (int p = 0; p < 4; ++p) {
            const int nn = tr + p * 16;
            uint4 va = {0, 0, 0, 0}, vb = {0, 0, 0, 0};
            if (i0 + tc8 < M) va = *(const uint4*)(A + (long)(n0 + nn) * lda + i0 + tc8);
            if (j0 + tc8 < N) vb = *(const uint4*)(B + (long)(n0 + nn) * ldb + j0 + tc8);
            const u16* ua = (const u16*)&va;
            const u16* ub = (const u16*)&vb;
#pragma unroll
            for (int e = 0; e < 8; ++e) {
                const int k = nn ^ ((e ^ sw) << 3);
                At[(tc8 + e) * 64 + k] = ua[e];
                Bl[(tc8 + e) * 64 + k] = ub[e];
            }
        }
        __syncthreads();
#pragma unroll
        for (int ks = 0; ks < 2; ++ks) {
            bfx8 af[4], bfr[4];
#pragma unroll
            for (int t = 0; t < 4; ++t) {
                const int ra = wm + t * 16 + l16;
                const int sa = ((ra & 7) ^ ((ra >> 3) & 7)) << 3;
                af[t]  = *(const bfx8*)(&At[ra * 64 + ((ks * 32 + q * 8) ^ sa)]);
                const int rb = wn + t * 16 + l16;
                const int sb = ((rb & 7) ^ ((rb >> 3) & 7)) << 3;
                bfr[t] = *(const bfx8*)(&Bl[rb * 64 + ((ks * 32 + q * 8) ^ sb)]);
            }
#pragma unroll
            for (int i = 0; i < 4; ++i)
#pragma unroll
                for (int j = 0; j < 4; ++j)
                    acc[i][j] = __builtin_amdgcn_mfma_f32_16x16x32_bf16(af[i], bfr[j], acc[i][j], 0, 0, 0);
        }
        __syncthreads();
    }

#pragma unroll
    for (int i = 0; i < 4; ++i)
#pragma unroll
        for (int j = 0; j < 4; ++j)
#pragma unroll
            for (int r = 0; r < 4; ++r) {
                const int gm = i0 + wm + i * 16 + q * 4 + r;
                const int gn = j0 + wn + j * 16 + l16;
                if (gm < M && gn < N)
                    C[coff + (long)gm * ldc + gn] = acc[i][j][r];
            }
}

// ---------------------------------------------------------------------------
// Tiled 512x512 transpose of a raw-input weight (f32 or bf16 per flag) -> bf16
// ---------------------------------------------------------------------------
__global__ void transpose_k(const void* __restrict__ in, u16* __restrict__ out,
                            const int* __restrict__ dflag)
{
    __shared__ __align__(16) u16 tile[64 * 72];
    const bool f32 = (*dflag != 0);
    const int r0 = blockIdx.x * 64, c0 = blockIdx.y * 64;
    const int tid = threadIdx.x;
    {
        const int tr = tid >> 3, tc = (tid & 7) * 8;
#pragma unroll
        for (int p = 0; p < 2; ++p) {
            const int r = tr + p * 32;
            const long base = (long)(r0 + r) * 512 + c0 + tc;
#pragma unroll
            for (int e = 0; e < 8; ++e) {
                tile[r * 72 + tc + e] = f32 ? f2bf(((const float*)in)[base + e])
                                            : ((const u16*)in)[base + e];
            }
        }
    }
    __syncthreads();
    {
        const int oc = tid >> 3, rn = (tid & 7) * 8;
#pragma unroll
        for (int p = 0; p < 2; ++p) {
            const int c = oc + p * 32;
            u16 res[8];
#pragma unroll
            for (int i = 0; i < 8; ++i) res[i] = tile[(rn + i) * 72 + c];
            *(uint4*)(out + (long)(c0 + c) * 512 + r0 + rn) = *(uint4*)res;
        }
    }
}

// LayerNorm row stats over 512 channels (ws bf16 input)
__global__ void ln_stats(const u16* __restrict__ in, float* __restrict__ mu,
                         float* __restrict__ rstd)
{
    const long row = blockIdx.x;
    const u16* p = in + row * 512;
    const int tid = threadIdx.x;
    const float v0 = b2f(p[tid * 2]), v1 = b2f(p[tid * 2 + 1]);
    float s = v0 + v1, sq = v0 * v0 + v1 * v1;
#pragma unroll
    for (int off = 32; off > 0; off >>= 1) {
        s  += __shfl_xor(s, off);
        sq += __shfl_xor(sq, off);
    }
    __shared__ float ls[4], lq[4];
    if ((tid & 63) == 0) { ls[tid >> 6] = s; lq[tid >> 6] = sq; }
    __syncthreads();
    if (tid == 0) {
        s = ls[0] + ls[1] + ls[2] + ls[3];
        sq = lq[0] + lq[1] + lq[2] + lq[3];
        const float m = s * (1.0f / 512.0f);
        float var = sq * (1.0f / 512.0f) - m * m;
        var = fmaxf(var, 0.0f);
        mu[row] = m;
        rstd[row] = rsqrtf(var + 1e-5f);
    }
}

// Apply LN in place on ws bf16
__global__ void ln_apply(u16* __restrict__ x, const float* __restrict__ mu,
                         const float* __restrict__ rstd,
                         const u16* __restrict__ g, const u16* __restrict__ b)
{
    const long idx = (long)blockIdx.x * 256 + threadIdx.x;
    const long row = idx >> 6;
    const int  c8  = (int)(idx & 63) * 8;
    u16* p = x + row * 512 + c8;
    uint4 v = *(uint4*)p;
    u16* u = (u16*)&v;
    const float m_ = mu[row], rs = rstd[row];
#pragma unroll
    for (int i = 0; i < 8; ++i)
        u[i] = f2bf((b2f(u[i]) - m_) * rs * b2f(g[c8 + i]) + b2f(b[c8 + i]));
    *(uint4*)p = v;
}

__global__ void zero_f32(float* __restrict__ p, int n)
{
    const int i = blockIdx.x * 256 + threadIdx.x;
    if (i < n) p[i] = 0.0f;
}

// Column sum-of-squares over n of ws-bf16 (B,4096,512), chunked + atomic
__global__ void colssq(const u16* __restrict__ in, float* __restrict__ ssq, int rowsPerChunk)
{
    const int b = blockIdx.x, cchunk = blockIdx.y, nchunk = blockIdx.z;
    const int c = cchunk * 256 + threadIdx.x;
    const u16* p = in + (long)b * 4096 * 512 + (long)nchunk * rowsPerChunk * 512 + c;
    float acc = 0.f;
    for (int n = 0; n < rowsPerChunk; ++n) {
        const float v = b2f(p[(long)n * 512]);
        acc += v * v;
    }
    atomicAdd(&ssq[b * 512 + c], acc);
}

// Row softmax over 512 (1/sqrt(512) pre-scale), f32 partials in -> bf16 out
__global__ void softmax_ab(const float* __restrict__ Ab, u16* __restrict__ out,
                           long sstride, int nsplit)
{
    const long row = blockIdx.x;
    const float* p = Ab + row * 512;
    const int tid = threadIdx.x;
    const float scale = 0.044194173824159216f;  // 1/sqrt(512)
    float a = 0.f, b = 0.f;
    for (int s = 0; s < nsplit; ++s) {
        a += p[(long)s * sstride + tid];
        b += p[(long)s * sstride + tid + 256];
    }
    a *= scale; b *= scale;
    float m = fmaxf(a, b);
#pragma unroll
    for (int off = 32; off > 0; off >>= 1) m = fmaxf(m, __shfl_xor(m, off));
    __shared__ float red[8];
    if ((tid & 63) == 0) red[tid >> 6] = m;
    __syncthreads();
    m = fmaxf(fmaxf(red[0], red[1]), fmaxf(red[2], red[3]));
    const float e0 = __expf(a - m), e1 = __expf(b - m);
    float s = e0 + e1;
#pragma unroll
    for (int off = 32; off > 0; off >>= 1) s += __shfl_xor(s, off);
    if ((tid & 63) == 0) red[4 + (tid >> 6)] = s;
    __syncthreads();
    s = red[4] + red[5] + red[6] + red[7];
    const float inv = 1.0f / fmaxf(s, 1e-30f);
    out[row * 512 + tid]       = f2bf(e0 * inv);
    out[row * 512 + tid + 256] = f2bf(e1 * inv);
}

// Row softmax over 64; logits = G[d][e]*rescale[h]/(||k_d||*||q_e||). Row=z*64+d.
// G comes as nsplit f32 partial buffers (K-split gemm), summed here.
__global__ void softmax_g(const float* __restrict__ G, const u16* __restrict__ rescale,
                          const float* __restrict__ ssq_k, const float* __restrict__ ssq_q,
                          u16* __restrict__ out, long sstride, int nsplit)
{
    const int row = blockIdx.x * 4 + (threadIdx.x >> 6);
    const int lane = threadIdx.x & 63;
    const int zz = row >> 6, d = row & 63;
    const int b_ = zz >> 3, h = zz & 7;
    const float rk = 1.0f / fmaxf(sqrtf(fmaxf(ssq_k[b_ * 512 + h * 64 + d], 0.f)), 1e-12f);
    const float rq = 1.0f / fmaxf(sqrtf(fmaxf(ssq_q[b_ * 512 + h * 64 + lane], 0.f)), 1e-12f);
    float gv = 0.f;
    for (int s = 0; s < nsplit; ++s)
        gv += G[(long)s * sstride + (long)row * 64 + lane];
    const float v = gv * rk * rq * b2f(rescale[h]);
    float m = v;
#pragma unroll
    for (int off = 32; off > 0; off >>= 1) m = fmaxf(m, __shfl_xor(m, off));
    const float e = __expf(v - m);
    float s = e;
#pragma unroll
    for (int off = 32; off > 0; off >>= 1) s += __shfl_xor(s, off);
    out[(long)row * 64 + lane] = f2bf(e / fmaxf(s, 1e-30f));
}

// Depthwise 3x3 SAME conv on NHWC (B,64,64,512) ws bf16, optional exact GeLU.
__global__ void dwconv3x3(const u16* __restrict__ in, const u16* __restrict__ w,
                          u16* __restrict__ out, int do_gelu)
{
    __shared__ u16 wl[4608];
    const int tid = threadIdx.x;
    for (int i = tid; i < 4608; i += 256) wl[i] = w[i];
    __syncthreads();
    const int b = blockIdx.x >> 6, y = blockIdx.x & 63;
    const long base = (long)b * 64 * 64 * 512;
    for (int t = 0; t < 16; ++t) {
        const int idx = t * 256 + tid;
        const int cg = idx & 63, x = idx >> 6;
        float acc[8] = {};
#pragma unroll
        for (int dy = -1; dy <= 1; ++dy) {
            const int yy = y + dy;
            if (yy < 0 || yy > 63) continue;
#pragma unroll
            for (int dx = -1; dx <= 1; ++dx) {
                const int xx = x + dx;
                if (xx < 0 || xx > 63) continue;
                const uint4 v = *(const uint4*)(in + base + ((long)yy * 64 + xx) * 512 + cg * 8);
                const u16* u = (const u16*)&v;
                const int wo = (dy + 1) * 3 + (dx + 1);
#pragma unroll
                for (int i = 0; i < 8; ++i)
                    acc[i] += b2f(u[i]) * b2f(wl[(cg * 8 + i) * 9 + wo]);
            }
        }
        u16 res[8];
#pragma unroll
        for (int i = 0; i < 8; ++i) {
            float v = acc[i];
            if (do_gelu) v = 0.5f * v * (1.0f + erff(v * 0.70710678118654752f));
            res[i] = f2bf(v);
        }
        *(uint4*)(out + base + ((long)y * 64 + x) * 512 + cg * 8) = *(uint4*)res;
    }
}

// ---------------------------------------------------------------------------
extern "C" void kernel_launch(void* const* d_in, const int* in_sizes, int n_in,
                              void* d_out, int out_size, void* d_ws, size_t ws_size,
                              hipStream_t stream)
{
    const void* x     = d_in[0];
    const void* illu  = d_in[1];
    const void* sem   = d_in[2];
    const void* WkS   = d_in[3];
    const void* WqS   = d_in[4];
    const void* WvS   = d_in[5];
    const void* ln_g  = d_in[6];
    const void* ln_b  = d_in[7];
    const void* Wq    = d_in[8];
    const void* Wk    = d_in[9];
    const void* Wv    = d_in[10];
    const void* resc  = d_in[11];
    const void* projW = d_in[12];
    const void* projB = d_in[13];
    const void* dw1   = d_in[14];
    const void* dw2   = d_in[15];
    (void)in_sizes; (void)n_in; (void)out_size; (void)ws_size;

    char* ws = (char*)d_ws;
    size_t off = 0;
    auto nxt = [&](size_t bytes) -> void* {
        void* p = ws + off;
        off += (bytes + 255) & ~(size_t)255;
        return p;
    };

    // Workspace ~119 MB
    u16* WqT   = (u16*)nxt(524288);
    u16* WkT   = (u16*)nxt(524288);
    u16* WvT   = (u16*)nxt(524288);
    u16* WkST  = (u16*)nxt(524288);
    u16* WqST  = (u16*)nxt(524288);
    u16* WvST  = (u16*)nxt(524288);
    u16* projT = (u16*)nxt(524288);
    u16* A = (u16*)nxt(33554432);   // 3 reusable 33.5MB slots
    u16* B = (u16*)nxt(33554432);
    u16* C = (u16*)nxt(33554432);
    float* Abf  = (float*)nxt(8388608);
    u16*   Absm = (u16*)nxt(4194304);
    float* mu   = (float*)nxt(131072);
    float* rs   = (float*)nxt(131072);
    float* ssq_q = (float*)nxt(16384);
    float* ssq_k = (float*)nxt(16384);
    float* Gf   = (float*)nxt(1048576);
    u16*   attn = (u16*)nxt(524288);
    int*   dflag = (int*)nxt(256);
    u16* ln_gc  = (u16*)nxt(1024);
    u16* ln_bc  = (u16*)nxt(1024);
    u16* projBc = (u16*)nxt(1024);
    u16* rescc  = (u16*)nxt(256);
    u16* dw1c   = (u16*)nxt(9216);
    u16* dw2c   = (u16*)nxt(9216);
    (void)Gf;

    const dim3 blk(256);

    // --- dtype detection + small-vector conversion -----------------------
    detect_dtype<<<dim3(1), blk, 0, stream>>>((const u16*)x, dflag);
    to_bf16<<<dim3(2), blk, 0, stream>>>(ln_g,  ln_gc,  512,  dflag);
    to_bf16<<<dim3(2), blk, 0, stream>>>(ln_b,  ln_bc,  512,  dflag);
    to_bf16<<<dim3(2), blk, 0, stream>>>(projB, projBc, 512,  dflag);
    to_bf16<<<dim3(1), blk, 0, stream>>>(resc,  rescc,  8,    dflag);
    to_bf16<<<dim3(18), blk, 0, stream>>>(dw1,  dw1c,   4608, dflag);
    to_bf16<<<dim3(18), blk, 0, stream>>>(dw2,  dw2c,   4608, dflag);

    auto wT = [&](const void* w, u16* o) {
        transpose_k<<<dim3(8, 8, 1), blk, 0, stream>>>(w, o, dflag);
    };
    wT(Wq, WqT); wT(Wk, WkT); wT(Wv, WvT);
    wT(WkS, WkST); wT(WqS, WqST); wT(WvS, WvST); wT(projW, projT);

    auto gemm = [&](const void* Ap, const u16* Btp, void* Cp, int M, int N, int K,
                    int lda, int ldb, int ldc, int nz, int nh,
                    long sAb, long sAh, long sBb, long sBh, long sCb, long sCh,
                    int epi, const u16* add1, long sAddB, long sAddH, int ldadd,
                    const u16* mul1, const u16* bias,
                    const int* aF32, const int* cF32) {
        dim3 g((M + 127) / 128, (N + 127) / 128, nz);
        gemm_bt<<<g, blk, 0, stream>>>(Ap, Btp, Cp, M, N, K, lda, ldb, ldc,
            sAb, sAh, sBb, sBh, sCb, sCh, nh, epi, add1, sAddB, sAddH, ldadd,
            mul1, bias, aF32, cF32);
    };

    // --- SIF channel attention -------------------------------------------
    gemm(illu, WkST, A, 32768, 512, 512, 512, 512, 512, 1, 1, 0,0,0,0,0,0, 1,
         nullptr,0,0,0, nullptr, nullptr, dflag, nullptr);
    ln_stats<<<dim3(32768), blk, 0, stream>>>(A, mu, rs);
    ln_apply<<<dim3(8192), blk, 0, stream>>>(A, mu, rs, ln_gc, ln_bc);
    gemm(sem, WqST, B, 32768, 512, 512, 512, 512, 512, 1, 1, 0,0,0,0,0,0, 1,
         nullptr,0,0,0, nullptr, nullptr, dflag, nullptr);
    ln_stats<<<dim3(32768), blk, 0, stream>>>(B, mu, rs);
    ln_apply<<<dim3(8192), blk, 0, stream>>>(B, mu, rs, ln_gc, ln_bc);
    // Ab[b][i][j] = sum_n Qn[n][i]*Kn[n][j], K-split x2 into f32 partials in C
    // z = s*8 + b (nh=8): A/B advance s*2048 rows, C partial stride 512*512*8
    float* Cf = (float*)C;
    gemm_at<<<dim3(4, 4, 16), blk, 0, stream>>>(B, A, Cf, 512, 512, 2048,
        512, 512, 512, 1048576, 2097152, 1048576, 2097152, 2097152, 262144, 8);
    softmax_ab<<<dim3(4096), blk, 0, stream>>>(Cf, Absm, 2097152, 2);

    // --- q/k paths + head attention matrix -------------------------------
    gemm(x, WqT, A, 32768, 512, 512, 512, 512, 512, 1, 1, 0,0,0,0,0,0, 1,
         nullptr,0,0,0, nullptr, nullptr, dflag, nullptr);
    zero_f32<<<dim3(16), blk, 0, stream>>>(ssq_q, 4096);
    colssq<<<dim3(8, 2, 16), blk, 0, stream>>>(A, ssq_q, 256);
    gemm(x, WkT, B, 32768, 512, 512, 512, 512, 512, 1, 1, 0,0,0,0,0,0, 1,
         nullptr,0,0,0, nullptr, nullptr, dflag, nullptr);
    zero_f32<<<dim3(16), blk, 0, stream>>>(ssq_k, 4096);
    colssq<<<dim3(8, 2, 16), blk, 0, stream>>>(B, ssq_k, 256);
    // G[z][d][e] = sum_n k_inp[n][h*64+d]*q_inp[n][h*64+e], z=b*8+h
    // K-split x4 into f32 partials in Abf (free after softmax_ab):
    // grid z = s*64 + z64 (nh=64); A/B advance s*1024 rows; partial stride 64*64*64
    gemm_at<<<dim3(1, 1, 256), blk, 0, stream>>>(B, A, Abf, 64, 64, 1024,
        512, 512, 64, 524288, 64, 524288, 64, 262144, 4096, 64);
    softmax_g<<<dim3(1024), blk, 0, stream>>>(Abf, rescc, ssq_k, ssq_q, attn,
        262144, 4);

    // --- v path + output --------------------------------------------------
    gemm(x, WvT, A, 32768, 512, 512, 512, 512, 512, 1, 1, 0,0,0,0,0,0, 1,
         nullptr,0,0,0, nullptr, nullptr, dflag, nullptr);
    gemm(illu, WvST, B, 32768, 512, 512, 512, 512, 512, 1, 1, 0,0,0,0,0,0, 1,
         nullptr,0,0,0, nullptr, nullptr, dflag, nullptr);
    // vg = (vsif@Absm^T + vsif) * v_inp -> C
    gemm(B, Absm, C, 4096, 512, 512, 512, 512, 512, 8, 1,
         2097152, 0, 262144, 0, 2097152, 0, 2, B, 2097152, 0, 512, A, nullptr,
         nullptr, nullptr);
    // o[b][n][h*64+d] = sum_e attn[z][d][e]*vg[b][n][h*64+e] -> B
    gemm(C, attn, B, 4096, 64, 64, 512, 64, 512, 64, 8,
         2097152, 64, 32768, 4096, 2097152, 64, 1, nullptr,0,0,0, nullptr, nullptr,
         nullptr, nullptr);
    // positional: p1 = gelu(dw(v_inp)) -> C ; p2 = dw(p1) -> A
    dwconv3x3<<<dim3(512), blk, 0, stream>>>(A, dw1c, C, 1);
    dwconv3x3<<<dim3(512), blk, 0, stream>>>(C, dw2c, A, 0);
    // out = o@proj_w + proj_b + p2 -> d_out (width per dflag)
    gemm(B, projT, d_out, 32768, 512, 512, 512, 512, 512, 1, 1, 0,0,0,0,0,0,
         3, A, 0, 0, 512, nullptr, projBc, nullptr, dflag);
}

// Round 2
// 1040.074 us; speedup vs baseline: 1.4983x; 1.0665x over previous
//
#include <hip/hip_runtime.h>

typedef unsigned short u16;
typedef unsigned int   u32;
typedef __bf16 bfx8 __attribute__((ext_vector_type(8)));
typedef float  f32x4 __attribute__((ext_vector_type(4)));

__device__ __forceinline__ float b2f(u16 v) {
    union { u32 u; float f; } c; c.u = ((u32)v) << 16; return c.f;
}
__device__ __forceinline__ u16 f2bf(float f) {
    union { float f; u32 u; } c; c.f = f;
    u32 u = c.u;
    return (u16)((u + 0x7fffu + ((u >> 16) & 1u)) >> 16);  // RNE
}
__device__ __forceinline__ u16 f2bf_hw(float f) {
    __bf16 h = (__bf16)f;
    return *(u16*)&h;
}

// Bijective XCD-chunked block swizzle (m204): physical blocks with the same
// (flat % 8) run on one XCD; give each XCD a contiguous chunk of logical work
// so blocks sharing an A-panel hit the same L2. Decomposition is by-fastest:
// w = (bz*gx + bx)*gy + by. All launch grids here have nwg % 8 == 0.
__device__ __forceinline__ void xcd_swz(int& bx, int& by, int& bz)
{
    const int gx = gridDim.x, gy = gridDim.y, gz = gridDim.z;
    const int nwg = gx * gy * gz;
    const int flat = blockIdx.x + gx * (blockIdx.y + gy * blockIdx.z);
    int w = flat;
    if ((nwg & 7) == 0) {
        const int q = nwg >> 3;
        w = (flat & 7) * q + (flat >> 3);
    }
    by = w % gy;
    const int t = w / gy;
    bx = t % gx;
    bz = t / gx;
}

// ---------------------------------------------------------------------------
// Input dtype detection: bf16 normal data -> nearly all even u16 elements have
// a plausible bf16 exponent; f32 data -> even u16s are mantissa halves
// (uniform bits, ~19% plausible). flag=1 means inputs are f32.
// ---------------------------------------------------------------------------
__global__ void detect_dtype(const u16* __restrict__ x, int* __restrict__ flag)
{
    const int tid = threadIdx.x;
    int cnt = 0;
    for (int i = tid; i < 2048; i += 256) {
        const u16 v = x[2 * i];
        const int e = (v >> 7) & 0xFF;
        if ((v & 0x7fff) == 0 || (e >= 96 && e <= 144)) cnt++;
    }
#pragma unroll
    for (int off = 32; off > 0; off >>= 1) cnt += __shfl_xor(cnt, off);
    __shared__ int sred[4];
    if ((tid & 63) == 0) sred[tid >> 6] = cnt;
    __syncthreads();
    if (tid == 0) {
        const int total = sred[0] + sred[1] + sred[2] + sred[3];
        flag[0] = (total < 1024) ? 1 : 0;
    }
}

// Convert small vector to bf16 (copy if already bf16)
__global__ void to_bf16(const void* __restrict__ in, u16* __restrict__ out,
                        int n, const int* __restrict__ flag)
{
    const int i = blockIdx.x * 256 + threadIdx.x;
    if (i < n)
        out[i] = (*flag) ? f2bf(((const float*)in)[i]) : ((const u16*)in)[i];
}

// Vectorized conversion, 8 elems/thread (n8 = n/8 uint4 outputs)
__global__ void to_bf16_v8(const void* __restrict__ in, u16* __restrict__ out,
                           int n8, const int* __restrict__ flag)
{
    const int i = blockIdx.x * 256 + threadIdx.x;
    if (i >= n8) return;
    uint4 r;
    if (*flag) {
        const float4 f0 = ((const float4*)in)[2 * i];
        const float4 f1 = ((const float4*)in)[2 * i + 1];
        u16* u = (u16*)&r;
        u[0] = f2bf_hw(f0.x); u[1] = f2bf_hw(f0.y);
        u[2] = f2bf_hw(f0.z); u[3] = f2bf_hw(f0.w);
        u[4] = f2bf_hw(f1.x); u[5] = f2bf_hw(f1.y);
        u[6] = f2bf_hw(f1.z); u[7] = f2bf_hw(f1.w);
    } else {
        r = ((const uint4*)in)[i];
    }
    ((uint4*)out)[i] = r;
}

// ---------------------------------------------------------------------------
// Batched GEMM: C[m][n] = sum_k A[m][k] * Bt[n][k]   (acc f32)
// A may be raw input (f32 or bf16, per aF32 flag); Bt always bf16.
// epi_mode: 1 = store; 2 = (acc+add1)*mul1; 3 = acc+bias+add1
// Store width: f32 if cF32 flag set, else bf16.
// ---------------------------------------------------------------------------
__global__ __launch_bounds__(256, 2)
void gemm_bt(const void* __restrict__ A, const u16* __restrict__ Bt,
             void* __restrict__ C,
             int M, int N, int K, int lda, int ldb, int ldc,
             long sAb, long sAh, long sBb, long sBh, long sCb, long sCh, int nh,
             int epi_mode, const u16* __restrict__ add1, long sAddB, long sAddH,
             int ldadd, const u16* __restrict__ mul1, const u16* __restrict__ bias,
             const int* __restrict__ aF32, const int* __restrict__ cF32)
{
    __shared__ __align__(16) u16 As[128 * 40];
    __shared__ __align__(16) u16 Bs[128 * 40];
    const bool af32 = aF32 && (*aF32 != 0);
    const bool cf32 = cF32 && (*cF32 != 0);
    int bx, by, bz;
    xcd_swz(bx, by, bz);
    const int z = bz, zb = z / nh, zh = z - zb * nh;
    const long aoff = (long)zb * sAb + (long)zh * sAh;
    Bt += (long)zb * sBb + (long)zh * sBh;
    const long coff = (long)zb * sCb + (long)zh * sCh;
    const int m0 = bx * 128, n0 = by * 128;
    const int tid = threadIdx.x, lane = tid & 63, wave = tid >> 6;
    const int wm = (wave >> 1) * 64, wn = (wave & 1) * 64;
    const int q = lane >> 4, l16 = lane & 15;
    const int rowL = tid >> 2, kcol = (tid & 3) * 8;

    f32x4 acc[4][4] = {};

    for (int k0 = 0; k0 < K; k0 += 32) {
#pragma unroll
        for (int p = 0; p < 2; ++p) {
            const int r = rowL + p * 64;
            uint4 va = {0, 0, 0, 0}, vb = {0, 0, 0, 0};
            if (m0 + r < M) {
                const long ai = aoff + (long)(m0 + r) * lda + k0 + kcol;
                if (af32) {
                    const float* Af = (const float*)A + ai;
                    float4 f0 = *(const float4*)Af;
                    float4 f1 = *(const float4*)(Af + 4);
                    u16* u = (u16*)&va;
                    u[0] = f2bf_hw(f0.x); u[1] = f2bf_hw(f0.y);
                    u[2] = f2bf_hw(f0.z); u[3] = f2bf_hw(f0.w);
                    u[4] = f2bf_hw(f1.x); u[5] = f2bf_hw(f1.y);
                    u[6] = f2bf_hw(f1.z); u[7] = f2bf_hw(f1.w);
                } else {
                    va = *(const uint4*)((const u16*)A + ai);
                }
            }
            if (n0 + r < N) vb = *(const uint4*)(Bt + (long)(n0 + r) * ldb + k0 + kcol);
            *(uint4*)(&As[r * 40 + kcol]) = va;
            *(uint4*)(&Bs[r * 40 + kcol]) = vb;
        }
        __syncthreads();
        bfx8 af[4], bfr[4];
#pragma unroll
        for (int t = 0; t < 4; ++t) {
            af[t]  = *(const bfx8*)(&As[(wm + t * 16 + l16) * 40 + q * 8]);
            bfr[t] = *(const bfx8*)(&Bs[(wn + t * 16 + l16) * 40 + q * 8]);
        }
#pragma unroll
        for (int i = 0; i < 4; ++i)
#pragma unroll
            for (int j = 0; j < 4; ++j)
                acc[i][j] = __builtin_amdgcn_mfma_f32_16x16x32_bf16(af[i], bfr[j], acc[i][j], 0, 0, 0);
        __syncthreads();
    }

#pragma unroll
    for (int i = 0; i < 4; ++i) {
#pragma unroll
        for (int j = 0; j < 4; ++j) {
#pragma unroll
            for (int r = 0; r < 4; ++r) {
                const int gm = m0 + wm + i * 16 + q * 4 + r;
                const int gn = n0 + wn + j * 16 + l16;
                if (gm < M && gn < N) {
                    float v = acc[i][j][r];
                    const long cidx = coff + (long)gm * ldc + gn;
                    if (epi_mode == 2) {
                        const long aidx = (long)zb * sAddB + (long)zh * sAddH + (long)gm * ldadd + gn;
                        v = (v + b2f(add1[aidx])) * b2f(mul1[aidx]);
                    } else if (epi_mode == 3) {
                        const long aidx = (long)gm * ldadd + gn;
                        v = v + b2f(bias[gn]) + b2f(add1[aidx]);
                    }
                    if (cf32) ((float*)C)[cidx] = v;
                    else      ((u16*)C)[cidx] = f2bf(v);
                }
            }
        }
    }
}

// ---------------------------------------------------------------------------
// AT-GEMM: C[i][j] = sum_n A[n][i] * B[n][j]  (contract rows; ws bf16 in, f32 out)
// LDS transpose staging uses stride 64 + XOR swizzle:
//   idx(i,k) = i*64 + (k ^ (((i&7) ^ ((i>>3)&7)) << 3))
// Same involution on the scalar u16 writes and the b128 fragment reads, so
// 16B alignment is preserved (XOR only touches k-bits 3..5).
// K-splitting is driven by the call site through the zb stride (sAb/sBb are
// n-offsets, sCb the f32 partial-buffer stride); consumers sum partials.
// ---------------------------------------------------------------------------
__global__ __launch_bounds__(256, 2)
void gemm_at(const u16* __restrict__ A, const u16* __restrict__ B,
             float* __restrict__ C,
             int M, int N, int K, int lda, int ldb, int ldc,
             long sAb, long sAh, long sBb, long sBh, long sCb, long sCh, int nh)
{
    __shared__ __align__(16) u16 At[128 * 64];
    __shared__ __align__(16) u16 Bl[128 * 64];
    int bx, by, bz;
    xcd_swz(bx, by, bz);
    const int z = bz, zb = z / nh, zh = z - zb * nh;
    A += (long)zb * sAb + (long)zh * sAh;
    B += (long)zb * sBb + (long)zh * sBh;
    const long coff = (long)zb * sCb + (long)zh * sCh;
    const int i0 = bx * 128, j0 = by * 128;
    const int tid = threadIdx.x, lane = tid & 63, wave = tid >> 6;
    const int wm = (wave >> 1) * 64, wn = (wave & 1) * 64;
    const int q = lane >> 4, l16 = lane & 15;
    const int tr = tid >> 4, tc8 = (tid & 15) * 8;
    const int sw = (tc8 >> 3) & 7;

    f32x4 acc[4][4] = {};

    for (int n0 = 0; n0 < K; n0 += 64) {
#pragma unroll
        for (int p = 0; p < 4; ++p) {
            const int nn = tr + p * 16;
            uint4 va = {0, 0, 0, 0}, vb = {0, 0, 0, 0};
            if (i0 + tc8 < M) va = *(const uint4*)(A + (long)(n0 + nn) * lda + i0 + tc8);
            if (j0 + tc8 < N) vb = *(const uint4*)(B + (long)(n0 + nn) * ldb + j0 + tc8);
            const u16* ua = (const u16*)&va;
            const u16* ub = (const u16*)&vb;
#pragma unroll
            for (int e = 0; e < 8; ++e) {
                const int k = nn ^ ((e ^ sw) << 3);
                At[(tc8 + e) * 64 + k] = ua[e];
                Bl[(tc8 + e) * 64 + k] = ub[e];
            }
        }
        __syncthreads();
#pragma unroll
        for (int ks = 0; ks < 2; ++ks) {
            bfx8 af[4], bfr[4];
#pragma unroll
            for (int t = 0; t < 4; ++t) {
                const int ra = wm + t * 16 + l16;
                const int sa = ((ra & 7) ^ ((ra >> 3) & 7)) << 3;
                af[t]  = *(const bfx8*)(&At[ra * 64 + ((ks * 32 + q * 8) ^ sa)]);
                const int rb = wn + t * 16 + l16;
                const int sb = ((rb & 7) ^ ((rb >> 3) & 7)) << 3;
                bfr[t] = *(const bfx8*)(&Bl[rb * 64 + ((ks * 32 + q * 8) ^ sb)]);
            }
#pragma unroll
            for (int i = 0; i < 4; ++i)
#pragma unroll
                for (int j = 0; j < 4; ++j)
                    acc[i][j] = __builtin_amdgcn_mfma_f32_16x16x32_bf16(af[i], bfr[j], acc[i][j], 0, 0, 0);
        }
        __syncthreads();
    }

#pragma unroll
    for (int i = 0; i < 4; ++i)
#pragma unroll
        for (int j = 0; j < 4; ++j)
#pragma unroll
            for (int r = 0; r < 4; ++r) {
                const int gm = i0 + wm + i * 16 + q * 4 + r;
                const int gn = j0 + wn + j * 16 + l16;
                if (gm < M && gn < N)
                    C[coff + (long)gm * ldc + gn] = acc[i][j][r];
            }
}

// ---------------------------------------------------------------------------
// Tiled 512x512 transpose of a raw-input weight (f32 or bf16 per flag) -> bf16
// ---------------------------------------------------------------------------
__global__ void transpose_k(const void* __restrict__ in, u16* __restrict__ out,
                            const int* __restrict__ dflag)
{
    __shared__ __align__(16) u16 tile[64 * 72];
    const bool f32 = (*dflag != 0);
    const int r0 = blockIdx.x * 64, c0 = blockIdx.y * 64;
    const int tid = threadIdx.x;
    {
        const int tr = tid >> 3, tc = (tid & 7) * 8;
#pragma unroll
        for (int p = 0; p < 2; ++p) {
            const int r = tr + p * 32;
            const long base = (long)(r0 + r) * 512 + c0 + tc;
#pragma unroll
            for (int e = 0; e < 8; ++e) {
                tile[r * 72 + tc + e] = f32 ? f2bf(((const float*)in)[base + e])
                                            : ((const u16*)in)[base + e];
            }
        }
    }
    __syncthreads();
    {
        const int oc = tid >> 3, rn = (tid & 7) * 8;
#pragma unroll
        for (int p = 0; p < 2; ++p) {
            const int c = oc + p * 32;
            u16 res[8];
#pragma unroll
            for (int i = 0; i < 8; ++i) res[i] = tile[(rn + i) * 72 + c];
            *(uint4*)(out + (long)(c0 + c) * 512 + r0 + rn) = *(uint4*)res;
        }
    }
}

// LayerNorm row stats over 512 channels (ws bf16 input)
__global__ void ln_stats(const u16* __restrict__ in, float* __restrict__ mu,
                         float* __restrict__ rstd)
{
    const long row = blockIdx.x;
    const u16* p = in + row * 512;
    const int tid = threadIdx.x;
    const float v0 = b2f(p[tid * 2]), v1 = b2f(p[tid * 2 + 1]);
    float s = v0 + v1, sq = v0 * v0 + v1 * v1;
#pragma unroll
    for (int off = 32; off > 0; off >>= 1) {
        s  += __shfl_xor(s, off);
        sq += __shfl_xor(sq, off);
    }
    __shared__ float ls[4], lq[4];
    if ((tid & 63) == 0) { ls[tid >> 6] = s; lq[tid >> 6] = sq; }
    __syncthreads();
    if (tid == 0) {
        s = ls[0] + ls[1] + ls[2] + ls[3];
        sq = lq[0] + lq[1] + lq[2] + lq[3];
        const float m = s * (1.0f / 512.0f);
        float var = sq * (1.0f / 512.0f) - m * m;
        var = fmaxf(var, 0.0f);
        mu[row] = m;
        rstd[row] = rsqrtf(var + 1e-5f);
    }
}

// Apply LN in place on ws bf16
__global__ void ln_apply(u16* __restrict__ x, const float* __restrict__ mu,
                         const float* __restrict__ rstd,
                         const u16* __restrict__ g, const u16* __restrict__ b)
{
    const long idx = (long)blockIdx.x * 256 + threadIdx.x;
    const long row = idx >> 6;
    const int  c8  = (int)(idx & 63) * 8;
    u16* p = x + row * 512 + c8;
    uint4 v = *(uint4*)p;
    u16* u = (u16*)&v;
    const float m_ = mu[row], rs = rstd[row];
#pragma unroll
    for (int i = 0; i < 8; ++i)
        u[i] = f2bf((b2f(u[i]) - m_) * rs * b2f(g[c8 + i]) + b2f(b[c8 + i]));
    *(uint4*)p = v;
}

__global__ void zero_f32(float* __restrict__ p, int n)
{
    const int i = blockIdx.x * 256 + threadIdx.x;
    if (i < n) p[i] = 0.0f;
}

// Column sum-of-squares over n of ws-bf16 (B,4096,512), chunked + atomic
__global__ void colssq(const u16* __restrict__ in, float* __restrict__ ssq, int rowsPerChunk)
{
    const int b = blockIdx.x, cchunk = blockIdx.y, nchunk = blockIdx.z;
    const int c = cchunk * 256 + threadIdx.x;
    const u16* p = in + (long)b * 4096 * 512 + (long)nchunk * rowsPerChunk * 512 + c;
    float acc = 0.f;
    for (int n = 0; n < rowsPerChunk; ++n) {
        const float v = b2f(p[(long)n * 512]);
        acc += v * v;
    }
    atomicAdd(&ssq[b * 512 + c], acc);
}

// Row softmax over 512 (1/sqrt(512) pre-scale), f32 partials in -> bf16 out
__global__ void softmax_ab(const float* __restrict__ Ab, u16* __restrict__ out,
                           long sstride, int nsplit)
{
    const long row = blockIdx.x;
    const float* p = Ab + row * 512;
    const int tid = threadIdx.x;
    const float scale = 0.044194173824159216f;  // 1/sqrt(512)
    float a = 0.f, b = 0.f;
    for (int s = 0; s < nsplit; ++s) {
        a += p[(long)s * sstride + tid];
        b += p[(long)s * sstride + tid + 256];
    }
    a *= scale; b *= scale;
    float m = fmaxf(a, b);
#pragma unroll
    for (int off = 32; off > 0; off >>= 1) m = fmaxf(m, __shfl_xor(m, off));
    __shared__ float red[8];
    if ((tid & 63) == 0) red[tid >> 6] = m;
    __syncthreads();
    m = fmaxf(fmaxf(red[0], red[1]), fmaxf(red[2], red[3]));
    const float e0 = __expf(a - m), e1 = __expf(b - m);
    float s = e0 + e1;
#pragma unroll
    for (int off = 32; off > 0; off >>= 1) s += __shfl_xor(s, off);
    if ((tid & 63) == 0) red[4 + (tid >> 6)] = s;
    __syncthreads();
    s = red[4] + red[5] + red[6] + red[7];
    const float inv = 1.0f / fmaxf(s, 1e-30f);
    out[row * 512 + tid]       = f2bf(e0 * inv);
    out[row * 512 + tid + 256] = f2bf(e1 * inv);
}

// Row softmax over 64; logits = G[d][e]*rescale[h]/(||k_d||*||q_e||). Row=z*64+d.
// G comes as nsplit f32 partial buffers (K-split gemm), summed here.
__global__ void softmax_g(const float* __restrict__ G, const u16* __restrict__ rescale,
                          const float* __restrict__ ssq_k, const float* __restrict__ ssq_q,
                          u16* __restrict__ out, long sstride, int nsplit)
{
    const int row = blockIdx.x * 4 + (threadIdx.x >> 6);
    const int lane = threadIdx.x & 63;
    const int zz = row >> 6, d = row & 63;
    const int b_ = zz >> 3, h = zz & 7;
    const float rk = 1.0f / fmaxf(sqrtf(fmaxf(ssq_k[b_ * 512 + h * 64 + d], 0.f)), 1e-12f);
    const float rq = 1.0f / fmaxf(sqrtf(fmaxf(ssq_q[b_ * 512 + h * 64 + lane], 0.f)), 1e-12f);
    float gv = 0.f;
    for (int s = 0; s < nsplit; ++s)
        gv += G[(long)s * sstride + (long)row * 64 + lane];
    const float v = gv * rk * rq * b2f(rescale[h]);
    float m = v;
#pragma unroll
    for (int off = 32; off > 0; off >>= 1) m = fmaxf(m, __shfl_xor(m, off));
    const float e = __expf(v - m);
    float s = e;
#pragma unroll
    for (int off = 32; off > 0; off >>= 1) s += __shfl_xor(s, off);
    out[(long)row * 64 + lane] = f2bf(e / fmaxf(s, 1e-30f));
}

// Depthwise 3x3 SAME conv on NHWC (B,64,64,512) ws bf16, optional exact GeLU.
__global__ void dwconv3x3(const u16* __restrict__ in, const u16* __restrict__ w,
                          u16* __restrict__ out, int do_gelu)
{
    __shared__ u16 wl[4608];
    const int tid = threadIdx.x;
    for (int i = tid; i < 4608; i += 256) wl[i] = w[i];
    __syncthreads();
    const int b = blockIdx.x >> 6, y = blockIdx.x & 63;
    const long base = (long)b * 64 * 64 * 512;
    for (int t = 0; t < 16; ++t) {
        const int idx = t * 256 + tid;
        const int cg = idx & 63, x = idx >> 6;
        float acc[8] = {};
#pragma unroll
        for (int dy = -1; dy <= 1; ++dy) {
            const int yy = y + dy;
            if (yy < 0 || yy > 63) continue;
#pragma unroll
            for (int dx = -1; dx <= 1; ++dx) {
                const int xx = x + dx;
                if (xx < 0 || xx > 63) continue;
                const uint4 v = *(const uint4*)(in + base + ((long)yy * 64 + xx) * 512 + cg * 8);
                const u16* u = (const u16*)&v;
                const int wo = (dy + 1) * 3 + (dx + 1);
#pragma unroll
                for (int i = 0; i < 8; ++i)
                    acc[i] += b2f(u[i]) * b2f(wl[(cg * 8 + i) * 9 + wo]);
            }
        }
        u16 res[8];
#pragma unroll
        for (int i = 0; i < 8; ++i) {
            float v = acc[i];
            if (do_gelu) v = 0.5f * v * (1.0f + erff(v * 0.70710678118654752f));
            res[i] = f2bf(v);
        }
        *(uint4*)(out + base + ((long)y * 64 + x) * 512 + cg * 8) = *(uint4*)res;
    }
}

// ---------------------------------------------------------------------------
extern "C" void kernel_launch(void* const* d_in, const int* in_sizes, int n_in,
                              void* d_out, int out_size, void* d_ws, size_t ws_size,
                              hipStream_t stream)
{
    const void* x     = d_in[0];
    const void* illu  = d_in[1];
    const void* sem   = d_in[2];
    const void* WkS   = d_in[3];
    const void* WqS   = d_in[4];
    const void* WvS   = d_in[5];
    const void* ln_g  = d_in[6];
    const void* ln_b  = d_in[7];
    const void* Wq    = d_in[8];
    const void* Wk    = d_in[9];
    const void* Wv    = d_in[10];
    const void* resc  = d_in[11];
    const void* projW = d_in[12];
    const void* projB = d_in[13];
    const void* dw1   = d_in[14];
    const void* dw2   = d_in[15];
    (void)in_sizes; (void)n_in; (void)out_size; (void)ws_size;

    char* ws = (char*)d_ws;
    size_t off = 0;
    auto nxt = [&](size_t bytes) -> void* {
        void* p = ws + off;
        off += (bytes + 255) & ~(size_t)255;
        return p;
    };

    // Workspace ~119 MB
    u16* WqT   = (u16*)nxt(524288);
    u16* WkT   = (u16*)nxt(524288);
    u16* WvT   = (u16*)nxt(524288);
    u16* WkST  = (u16*)nxt(524288);
    u16* WqST  = (u16*)nxt(524288);
    u16* WvST  = (u16*)nxt(524288);
    u16* projT = (u16*)nxt(524288);
    u16* A = (u16*)nxt(33554432);   // 3 reusable 33.5MB slots
    u16* B = (u16*)nxt(33554432);
    u16* C = (u16*)nxt(33554432);
    float* Abf  = (float*)nxt(8388608);
    u16*   Absm = (u16*)nxt(4194304);
    float* mu   = (float*)nxt(131072);
    float* rs   = (float*)nxt(131072);
    float* ssq_q = (float*)nxt(16384);
    float* ssq_k = (float*)nxt(16384);
    float* Gf   = (float*)nxt(1048576);
    u16*   attn = (u16*)nxt(524288);
    int*   dflag = (int*)nxt(256);
    u16* ln_gc  = (u16*)nxt(1024);
    u16* ln_bc  = (u16*)nxt(1024);
    u16* projBc = (u16*)nxt(1024);
    u16* rescc  = (u16*)nxt(256);
    u16* dw1c   = (u16*)nxt(9216);
    u16* dw2c   = (u16*)nxt(9216);
    (void)Gf;

    const dim3 blk(256);

    // --- dtype detection + small-vector conversion -----------------------
    detect_dtype<<<dim3(1), blk, 0, stream>>>((const u16*)x, dflag);
    to_bf16<<<dim3(2), blk, 0, stream>>>(ln_g,  ln_gc,  512,  dflag);
    to_bf16<<<dim3(2), blk, 0, stream>>>(ln_b,  ln_bc,  512,  dflag);
    to_bf16<<<dim3(2), blk, 0, stream>>>(projB, projBc, 512,  dflag);
    to_bf16<<<dim3(1), blk, 0, stream>>>(resc,  rescc,  8,    dflag);
    to_bf16<<<dim3(18), blk, 0, stream>>>(dw1,  dw1c,   4608, dflag);
    to_bf16<<<dim3(18), blk, 0, stream>>>(dw2,  dw2c,   4608, dflag);

    auto wT = [&](const void* w, u16* o) {
        transpose_k<<<dim3(8, 8, 1), blk, 0, stream>>>(w, o, dflag);
    };
    wT(Wq, WqT); wT(Wk, WkT); wT(Wv, WvT);
    wT(WkS, WkST); wT(WqS, WqST); wT(WvS, WvST); wT(projW, projT);

    auto gemm = [&](const void* Ap, const u16* Btp, void* Cp, int M, int N, int K,
                    int lda, int ldb, int ldc, int nz, int nh,
                    long sAb, long sAh, long sBb, long sBh, long sCb, long sCh,
                    int epi, const u16* add1, long sAddB, long sAddH, int ldadd,
                    const u16* mul1, const u16* bias,
                    const int* aF32, const int* cF32) {
        dim3 g((M + 127) / 128, (N + 127) / 128, nz);
        gemm_bt<<<g, blk, 0, stream>>>(Ap, Btp, Cp, M, N, K, lda, ldb, ldc,
            sAb, sAh, sBb, sBh, sCb, sCh, nh, epi, add1, sAddB, sAddH, ldadd,
            mul1, bias, aF32, cF32);
    };

    // --- SIF channel attention -------------------------------------------
    gemm(illu, WkST, A, 32768, 512, 512, 512, 512, 512, 1, 1, 0,0,0,0,0,0, 1,
         nullptr,0,0,0, nullptr, nullptr, dflag, nullptr);
    ln_stats<<<dim3(32768), blk, 0, stream>>>(A, mu, rs);
    ln_apply<<<dim3(8192), blk, 0, stream>>>(A, mu, rs, ln_gc, ln_bc);
    gemm(sem, WqST, B, 32768, 512, 512, 512, 512, 512, 1, 1, 0,0,0,0,0,0, 1,
         nullptr,0,0,0, nullptr, nullptr, dflag, nullptr);
    ln_stats<<<dim3(32768), blk, 0, stream>>>(B, mu, rs);
    ln_apply<<<dim3(8192), blk, 0, stream>>>(B, mu, rs, ln_gc, ln_bc);
    // Ab[b][i][j] = sum_n Qn[n][i]*Kn[n][j], K-split x4 into f32 partials in C
    // z = s*8 + b (nh=8): A/B advance s*1024 rows, partial stride 512*512*8
    float* Cf = (float*)C;
    gemm_at<<<dim3(4, 4, 32), blk, 0, stream>>>(B, A, Cf, 512, 512, 1024,
        512, 512, 512, 524288, 2097152, 524288, 2097152, 2097152, 262144, 8);
    softmax_ab<<<dim3(4096), blk, 0, stream>>>(Cf, Absm, 2097152, 4);

    // --- q/k paths + head attention matrix -------------------------------
    // Convert x once to bf16 into C (free between softmax_ab and vg-gemm)
    u16* xb = C;
    to_bf16_v8<<<dim3(8192), blk, 0, stream>>>(x, xb, 2097152, dflag);
    gemm(xb, WqT, A, 32768, 512, 512, 512, 512, 512, 1, 1, 0,0,0,0,0,0, 1,
         nullptr,0,0,0, nullptr, nullptr, nullptr, nullptr);
    zero_f32<<<dim3(16), blk, 0, stream>>>(ssq_q, 4096);
    colssq<<<dim3(8, 2, 16), blk, 0, stream>>>(A, ssq_q, 256);
    gemm(xb, WkT, B, 32768, 512, 512, 512, 512, 512, 1, 1, 0,0,0,0,0,0, 1,
         nullptr,0,0,0, nullptr, nullptr, nullptr, nullptr);
    zero_f32<<<dim3(16), blk, 0, stream>>>(ssq_k, 4096);
    colssq<<<dim3(8, 2, 16), blk, 0, stream>>>(B, ssq_k, 256);
    // G[z][d][e] = sum_n k_inp[n][h*64+d]*q_inp[n][h*64+e], z=b*8+h
    // K-split x8 into f32 partials in Abf: grid z = s*64 + z64 (nh=64);
    // A/B advance s*512 rows; partial stride 64*64*64
    gemm_at<<<dim3(1, 1, 512), blk, 0, stream>>>(B, A, Abf, 64, 64, 512,
        512, 512, 64, 262144, 64, 262144, 64, 262144, 4096, 64);
    softmax_g<<<dim3(1024), blk, 0, stream>>>(Abf, rescc, ssq_k, ssq_q, attn,
        262144, 8);

    // --- v path + output --------------------------------------------------
    gemm(xb, WvT, A, 32768, 512, 512, 512, 512, 512, 1, 1, 0,0,0,0,0,0, 1,
         nullptr,0,0,0, nullptr, nullptr, nullptr, nullptr);
    gemm(illu, WvST, B, 32768, 512, 512, 512, 512, 512, 1, 1, 0,0,0,0,0,0, 1,
         nullptr,0,0,0, nullptr, nullptr, dflag, nullptr);
    // vg = (vsif@Absm^T + vsif) * v_inp -> C  (xb dead now)
    gemm(B, Absm, C, 4096, 512, 512, 512, 512, 512, 8, 1,
         2097152, 0, 262144, 0, 2097152, 0, 2, B, 2097152, 0, 512, A, nullptr,
         nullptr, nullptr);
    // o[b][n][h*64+d] = sum_e attn[z][d][e]*vg[b][n][h*64+e] -> B
    gemm(C, attn, B, 4096, 64, 64, 512, 64, 512, 64, 8,
         2097152, 64, 32768, 4096, 2097152, 64, 1, nullptr,0,0,0, nullptr, nullptr,
         nullptr, nullptr);
    // positional: p1 = gelu(dw(v_inp)) -> C ; p2 = dw(p1) -> A
    dwconv3x3<<<dim3(512), blk, 0, stream>>>(A, dw1c, C, 1);
    dwconv3x3<<<dim3(512), blk, 0, stream>>>(C, dw2c, A, 0);
    // out = o@proj_w + proj_b + p2 -> d_out (width per dflag)
    gemm(B, projT, d_out, 32768, 512, 512, 512, 512, 512, 1, 1, 0,0,0,0,0,0,
         3, A, 0, 0, 512, nullptr, projBc, nullptr, dflag);
}

// Round 4
// 937.041 us; speedup vs baseline: 1.6631x; 1.1100x over previous
//
#include <hip/hip_runtime.h>

typedef unsigned short u16;
typedef unsigned int   u32;
typedef __bf16 bfx8 __attribute__((ext_vector_type(8)));
typedef float  f32x4 __attribute__((ext_vector_type(4)));

__device__ __forceinline__ float b2f(u16 v) {
    union { u32 u; float f; } c; c.u = ((u32)v) << 16; return c.f;
}
__device__ __forceinline__ u16 f2bf(float f) {
    union { float f; u32 u; } c; c.f = f;
    u32 u = c.u;
    return (u16)((u + 0x7fffu + ((u >> 16) & 1u)) >> 16);  // RNE
}
__device__ __forceinline__ u16 f2bf_hw(float f) {
    __bf16 h = (__bf16)f;
    return *(u16*)&h;
}

// Async global->LDS DMA, 16B per lane. LDS dest is wave-uniform base + lane*16
// (hardware takes readfirstlane of the pointer); global src is per-lane.
__device__ __forceinline__ void gld_lds16(const u16* g, u16* l)
{
    __builtin_amdgcn_global_load_lds(
        (const __attribute__((address_space(1))) void*)g,
        (__attribute__((address_space(3))) void*)l, 16, 0, 0);
}

// Bijective XCD-chunked block swizzle (m204): physical blocks with the same
// (flat % 8) run on one XCD; give each XCD a contiguous chunk of logical work
// so blocks sharing an A-panel hit the same L2. Decomposition is by-fastest:
// w = (bz*gx + bx)*gy + by. All launch grids here have nwg % 8 == 0.
__device__ __forceinline__ void xcd_swz(int& bx, int& by, int& bz)
{
    const int gx = gridDim.x, gy = gridDim.y, gz = gridDim.z;
    const int nwg = gx * gy * gz;
    const int flat = blockIdx.x + gx * (blockIdx.y + gy * blockIdx.z);
    int w = flat;
    if ((nwg & 7) == 0) {
        const int q = nwg >> 3;
        w = (flat & 7) * q + (flat >> 3);
    }
    by = w % gy;
    const int t = w / gy;
    bx = t % gx;
    bz = t / gx;
}

// ---------------------------------------------------------------------------
// Input dtype detection: bf16 normal data -> nearly all even u16 elements have
// a plausible bf16 exponent; f32 data -> even u16s are mantissa halves
// (uniform bits, ~19% plausible). flag=1 means inputs are f32.
// ---------------------------------------------------------------------------
__global__ void detect_dtype(const u16* __restrict__ x, int* __restrict__ flag)
{
    const int tid = threadIdx.x;
    int cnt = 0;
    for (int i = tid; i < 2048; i += 256) {
        const u16 v = x[2 * i];
        const int e = (v >> 7) & 0xFF;
        if ((v & 0x7fff) == 0 || (e >= 96 && e <= 144)) cnt++;
    }
#pragma unroll
    for (int off = 32; off > 0; off >>= 1) cnt += __shfl_xor(cnt, off);
    __shared__ int sred[4];
    if ((tid & 63) == 0) sred[tid >> 6] = cnt;
    __syncthreads();
    if (tid == 0) {
        const int total = sred[0] + sred[1] + sred[2] + sred[3];
        flag[0] = (total < 1024) ? 1 : 0;
    }
}

// Convert small vector to bf16 (copy if already bf16)
__global__ void to_bf16(const void* __restrict__ in, u16* __restrict__ out,
                        int n, const int* __restrict__ flag)
{
    const int i = blockIdx.x * 256 + threadIdx.x;
    if (i < n)
        out[i] = (*flag) ? f2bf(((const float*)in)[i]) : ((const u16*)in)[i];
}

// Vectorized conversion, 8 elems/thread (n8 = n/8 uint4 outputs)
__global__ void to_bf16_v8(const void* __restrict__ in, u16* __restrict__ out,
                           int n8, const int* __restrict__ flag)
{
    const int i = blockIdx.x * 256 + threadIdx.x;
    if (i >= n8) return;
    uint4 r;
    if (*flag) {
        const float4 f0 = ((const float4*)in)[2 * i];
        const float4 f1 = ((const float4*)in)[2 * i + 1];
        u16* u = (u16*)&r;
        u[0] = f2bf_hw(f0.x); u[1] = f2bf_hw(f0.y);
        u[2] = f2bf_hw(f0.z); u[3] = f2bf_hw(f0.w);
        u[4] = f2bf_hw(f1.x); u[5] = f2bf_hw(f1.y);
        u[6] = f2bf_hw(f1.z); u[7] = f2bf_hw(f1.w);
    } else {
        r = ((const uint4*)in)[i];
    }
    ((uint4*)out)[i] = r;
}

// ---------------------------------------------------------------------------
// FAST batched GEMM (bf16 A): C[m][n] = sum_k A[m][k] * Bt[n][k]
// Requires M%128==0, N%128==0, K%32==0 (no guards).
// Staging via global_load_lds width=16 into LINEAR LDS (ld=32 u16).
// Bank-conflict fix: LDS chunk (r,c) holds global chunk c ^ ((r>>1)&3);
// fragment reads apply the same involution -> uniform ~2-way (free) banking.
// epi_mode: 1 = store; 2 = (acc+add1)*mul1; 3 = acc+bias+add1
// ---------------------------------------------------------------------------
__global__ __launch_bounds__(256, 2)
void gemm_btf(const u16* __restrict__ A, const u16* __restrict__ Bt,
              void* __restrict__ C,
              int M, int N, int K, int lda, int ldb, int ldc,
              long sAb, long sAh, long sBb, long sBh, long sCb, long sCh, int nh,
              int epi_mode, const u16* __restrict__ add1, long sAddB, long sAddH,
              int ldadd, const u16* __restrict__ mul1, const u16* __restrict__ bias,
              const int* __restrict__ cF32)
{
    __shared__ __align__(16) u16 As[128 * 32];
    __shared__ __align__(16) u16 Bs[128 * 32];
    const bool cf32 = cF32 && (*cF32 != 0);
    int bx, by, bz;
    xcd_swz(bx, by, bz);
    const int zb = bz / nh, zh = bz - zb * nh;
    const int m0 = bx * 128, n0 = by * 128;
    const int tid = threadIdx.x, lane = tid & 63, wave = tid >> 6;
    const int wm = (wave >> 1) * 64, wn = (wave & 1) * 64;
    const int q = lane >> 4, l16 = lane & 15;

    // staging geometry: 16B chunk f = p*256 + tid (p=0,1); r=f>>2, c=f&3
    const int r0 = tid >> 2, c0 = tid & 3;
    const int cs = (c0 ^ ((r0 >> 1) & 3)) * 8;   // global u16 col (same for r0+64)
    const u16* pA = A + (long)zb * sAb + (long)zh * sAh;
    const u16* pB = Bt + (long)zb * sBb + (long)zh * sBh;
    const u16* gA0 = pA + (long)(m0 + r0) * lda + cs;
    const u16* gA1 = pA + (long)(m0 + r0 + 64) * lda + cs;
    const u16* gB0 = pB + (long)(n0 + r0) * ldb + cs;
    const u16* gB1 = pB + (long)(n0 + r0 + 64) * ldb + cs;
    u16* lA0 = &As[tid * 8];
    u16* lA1 = &As[(256 + tid) * 8];
    u16* lB0 = &Bs[tid * 8];
    u16* lB1 = &Bs[(256 + tid) * 8];

    // fragment-read swizzled chunk offset (u16 units); same for all t and both mats
    const int fco = (q ^ ((l16 >> 1) & 3)) * 8;

    f32x4 acc[4][4] = {};

    for (int k0 = 0; k0 < K; k0 += 32) {
        gld_lds16(gA0 + k0, lA0);
        gld_lds16(gA1 + k0, lA1);
        gld_lds16(gB0 + k0, lB0);
        gld_lds16(gB1 + k0, lB1);
        __syncthreads();
        bfx8 af[4], bfr[4];
#pragma unroll
        for (int t = 0; t < 4; ++t) {
            af[t]  = *(const bfx8*)(&As[(wm + t * 16 + l16) * 32 + fco]);
            bfr[t] = *(const bfx8*)(&Bs[(wn + t * 16 + l16) * 32 + fco]);
        }
#pragma unroll
        for (int i = 0; i < 4; ++i)
#pragma unroll
            for (int j = 0; j < 4; ++j)
                acc[i][j] = __builtin_amdgcn_mfma_f32_16x16x32_bf16(af[i], bfr[j], acc[i][j], 0, 0, 0);
        __syncthreads();
    }

    const long coff = (long)zb * sCb + (long)zh * sCh;
#pragma unroll
    for (int i = 0; i < 4; ++i) {
#pragma unroll
        for (int j = 0; j < 4; ++j) {
#pragma unroll
            for (int r = 0; r < 4; ++r) {
                const int gm = m0 + wm + i * 16 + q * 4 + r;
                const int gn = n0 + wn + j * 16 + l16;
                float v = acc[i][j][r];
                const long cidx = coff + (long)gm * ldc + gn;
                if (epi_mode == 2) {
                    const long aidx = (long)zb * sAddB + (long)zh * sAddH + (long)gm * ldadd + gn;
                    v = (v + b2f(add1[aidx])) * b2f(mul1[aidx]);
                } else if (epi_mode == 3) {
                    const long aidx = (long)gm * ldadd + gn;
                    v = v + b2f(bias[gn]) + b2f(add1[aidx]);
                }
                if (cf32) ((float*)C)[cidx] = v;
                else      ((u16*)C)[cidx] = f2bf(v);
            }
        }
    }
}

// ---------------------------------------------------------------------------
// Guarded batched GEMM (kept for the small o-gemm, N=64 < tile)
// ---------------------------------------------------------------------------
__global__ __launch_bounds__(256, 2)
void gemm_bt(const void* __restrict__ A, const u16* __restrict__ Bt,
             void* __restrict__ C,
             int M, int N, int K, int lda, int ldb, int ldc,
             long sAb, long sAh, long sBb, long sBh, long sCb, long sCh, int nh,
             int epi_mode, const u16* __restrict__ add1, long sAddB, long sAddH,
             int ldadd, const u16* __restrict__ mul1, const u16* __restrict__ bias,
             const int* __restrict__ aF32, const int* __restrict__ cF32)
{
    __shared__ __align__(16) u16 As[128 * 40];
    __shared__ __align__(16) u16 Bs[128 * 40];
    const bool af32 = aF32 && (*aF32 != 0);
    const bool cf32 = cF32 && (*cF32 != 0);
    int bx, by, bz;
    xcd_swz(bx, by, bz);
    const int z = bz, zb = z / nh, zh = z - zb * nh;
    const long aoff = (long)zb * sAb + (long)zh * sAh;
    Bt += (long)zb * sBb + (long)zh * sBh;
    const long coff = (long)zb * sCb + (long)zh * sCh;
    const int m0 = bx * 128, n0 = by * 128;
    const int tid = threadIdx.x, lane = tid & 63, wave = tid >> 6;
    const int wm = (wave >> 1) * 64, wn = (wave & 1) * 64;
    const int q = lane >> 4, l16 = lane & 15;
    const int rowL = tid >> 2, kcol = (tid & 3) * 8;

    f32x4 acc[4][4] = {};

    for (int k0 = 0; k0 < K; k0 += 32) {
#pragma unroll
        for (int p = 0; p < 2; ++p) {
            const int r = rowL + p * 64;
            uint4 va = {0, 0, 0, 0}, vb = {0, 0, 0, 0};
            if (m0 + r < M) {
                const long ai = aoff + (long)(m0 + r) * lda + k0 + kcol;
                if (af32) {
                    const float* Af = (const float*)A + ai;
                    float4 f0 = *(const float4*)Af;
                    float4 f1 = *(const float4*)(Af + 4);
                    u16* u = (u16*)&va;
                    u[0] = f2bf_hw(f0.x); u[1] = f2bf_hw(f0.y);
                    u[2] = f2bf_hw(f0.z); u[3] = f2bf_hw(f0.w);
                    u[4] = f2bf_hw(f1.x); u[5] = f2bf_hw(f1.y);
                    u[6] = f2bf_hw(f1.z); u[7] = f2bf_hw(f1.w);
                } else {
                    va = *(const uint4*)((const u16*)A + ai);
                }
            }
            if (n0 + r < N) vb = *(const uint4*)(Bt + (long)(n0 + r) * ldb + k0 + kcol);
            *(uint4*)(&As[r * 40 + kcol]) = va;
            *(uint4*)(&Bs[r * 40 + kcol]) = vb;
        }
        __syncthreads();
        bfx8 af[4], bfr[4];
#pragma unroll
        for (int t = 0; t < 4; ++t) {
            af[t]  = *(const bfx8*)(&As[(wm + t * 16 + l16) * 40 + q * 8]);
            bfr[t] = *(const bfx8*)(&Bs[(wn + t * 16 + l16) * 40 + q * 8]);
        }
#pragma unroll
        for (int i = 0; i < 4; ++i)
#pragma unroll
            for (int j = 0; j < 4; ++j)
                acc[i][j] = __builtin_amdgcn_mfma_f32_16x16x32_bf16(af[i], bfr[j], acc[i][j], 0, 0, 0);
        __syncthreads();
    }

#pragma unroll
    for (int i = 0; i < 4; ++i) {
#pragma unroll
        for (int j = 0; j < 4; ++j) {
#pragma unroll
            for (int r = 0; r < 4; ++r) {
                const int gm = m0 + wm + i * 16 + q * 4 + r;
                const int gn = n0 + wn + j * 16 + l16;
                if (gm < M && gn < N) {
                    float v = acc[i][j][r];
                    const long cidx = coff + (long)gm * ldc + gn;
                    if (epi_mode == 2) {
                        const long aidx = (long)zb * sAddB + (long)zh * sAddH + (long)gm * ldadd + gn;
                        v = (v + b2f(add1[aidx])) * b2f(mul1[aidx]);
                    } else if (epi_mode == 3) {
                        const long aidx = (long)gm * ldadd + gn;
                        v = v + b2f(bias[gn]) + b2f(add1[aidx]);
                    }
                    if (cf32) ((float*)C)[cidx] = v;
                    else      ((u16*)C)[cidx] = f2bf(v);
                }
            }
        }
    }
}

// ---------------------------------------------------------------------------
// AT-GEMM: C[i][j] = sum_n A[n][i] * B[n][j]  (contract rows; ws bf16 in, f32 out)
// LDS transpose staging uses stride 64 + XOR swizzle (see round 1 notes).
// ---------------------------------------------------------------------------
__global__ __launch_bounds__(256, 2)
void gemm_at(const u16* __restrict__ A, const u16* __restrict__ B,
             float* __restrict__ C,
             int M, int N, int K, int lda, int ldb, int ldc,
             long sAb, long sAh, long sBb, long sBh, long sCb, long sCh, int nh)
{
    __shared__ __align__(16) u16 At[128 * 64];
    __shared__ __align__(16) u16 Bl[128 * 64];
    int bx, by, bz;
    xcd_swz(bx, by, bz);
    const int z = bz, zb = z / nh, zh = z - zb * nh;
    A += (long)zb * sAb + (long)zh * sAh;
    B += (long)zb * sBb + (long)zh * sBh;
    const long coff = (long)zb * sCb + (long)zh * sCh;
    const int i0 = bx * 128, j0 = by * 128;
    const int tid = threadIdx.x, lane = tid & 63, wave = tid >> 6;
    const int wm = (wave >> 1) * 64, wn = (wave & 1) * 64;
    const int q = lane >> 4, l16 = lane & 15;
    const int tr = tid >> 4, tc8 = (tid & 15) * 8;
    const int sw = (tc8 >> 3) & 7;

    f32x4 acc[4][4] = {};

    for (int n0 = 0; n0 < K; n0 += 64) {
#pragma unroll
        for (int p = 0; p < 4; ++p) {
            const int nn = tr + p * 16;
            uint4 va = {0, 0, 0, 0}, vb = {0, 0, 0, 0};
            if (i0 + tc8 < M) va = *(const uint4*)(A + (long)(n0 + nn) * lda + i0 + tc8);
            if (j0 + tc8 < N) vb = *(const uint4*)(B + (long)(n0 + nn) * ldb + j0 + tc8);
            const u16* ua = (const u16*)&va;
            const u16* ub = (const u16*)&vb;
#pragma unroll
            for (int e = 0; e < 8; ++e) {
                const int k = nn ^ ((e ^ sw) << 3);
                At[(tc8 + e) * 64 + k] = ua[e];
                Bl[(tc8 + e) * 64 + k] = ub[e];
            }
        }
        __syncthreads();
#pragma unroll
        for (int ks = 0; ks < 2; ++ks) {
            bfx8 af[4], bfr[4];
#pragma unroll
            for (int t = 0; t < 4; ++t) {
                const int ra = wm + t * 16 + l16;
                const int sa = ((ra & 7) ^ ((ra >> 3) & 7)) << 3;
                af[t]  = *(const bfx8*)(&At[ra * 64 + ((ks * 32 + q * 8) ^ sa)]);
                const int rb = wn + t * 16 + l16;
                const int sb = ((rb & 7) ^ ((rb >> 3) & 7)) << 3;
                bfr[t] = *(const bfx8*)(&Bl[rb * 64 + ((ks * 32 + q * 8) ^ sb)]);
            }
#pragma unroll
            for (int i = 0; i < 4; ++i)
#pragma unroll
                for (int j = 0; j < 4; ++j)
                    acc[i][j] = __builtin_amdgcn_mfma_f32_16x16x32_bf16(af[i], bfr[j], acc[i][j], 0, 0, 0);
        }
        __syncthreads();
    }

#pragma unroll
    for (int i = 0; i < 4; ++i)
#pragma unroll
        for (int j = 0; j < 4; ++j)
#pragma unroll
            for (int r = 0; r < 4; ++r) {
                const int gm = i0 + wm + i * 16 + q * 4 + r;
                const int gn = j0 + wn + j * 16 + l16;
                if (gm < M && gn < N)
                    C[coff + (long)gm * ldc + gn] = acc[i][j][r];
            }
}

// ---------------------------------------------------------------------------
// Tiled 512x512 transpose of a raw-input weight (f32 or bf16 per flag) -> bf16
// ---------------------------------------------------------------------------
__global__ void transpose_k(const void* __restrict__ in, u16* __restrict__ out,
                            const int* __restrict__ dflag)
{
    __shared__ __align__(16) u16 tile[64 * 72];
    const bool f32 = (*dflag != 0);
    const int r0 = blockIdx.x * 64, c0 = blockIdx.y * 64;
    const int tid = threadIdx.x;
    {
        const int tr = tid >> 3, tc = (tid & 7) * 8;
#pragma unroll
        for (int p = 0; p < 2; ++p) {
            const int r = tr + p * 32;
            const long base = (long)(r0 + r) * 512 + c0 + tc;
#pragma unroll
            for (int e = 0; e < 8; ++e) {
                tile[r * 72 + tc + e] = f32 ? f2bf(((const float*)in)[base + e])
                                            : ((const u16*)in)[base + e];
            }
        }
    }
    __syncthreads();
    {
        const int oc = tid >> 3, rn = (tid & 7) * 8;
#pragma unroll
        for (int p = 0; p < 2; ++p) {
            const int c = oc + p * 32;
            u16 res[8];
#pragma unroll
            for (int i = 0; i < 8; ++i) res[i] = tile[(rn + i) * 72 + c];
            *(uint4*)(out + (long)(c0 + c) * 512 + r0 + rn) = *(uint4*)res;
        }
    }
}

// Fused LayerNorm over 512 channels, in place on ws bf16.
// One 64-lane wave per row; 8 u16 per lane (uint4 load/store).
__global__ void ln_fused(u16* __restrict__ x, const u16* __restrict__ g,
                         const u16* __restrict__ b)
{
    const long row = (long)blockIdx.x * 4 + (threadIdx.x >> 6);
    const int lane = threadIdx.x & 63;
    const int c8 = lane * 8;
    u16* p = x + row * 512 + c8;
    uint4 v = *(uint4*)p;
    u16* u = (u16*)&v;
    float f[8];
    float s = 0.f, sq = 0.f;
#pragma unroll
    for (int i = 0; i < 8; ++i) { f[i] = b2f(u[i]); s += f[i]; sq += f[i] * f[i]; }
#pragma unroll
    for (int off = 32; off > 0; off >>= 1) {
        s  += __shfl_xor(s, off);
        sq += __shfl_xor(sq, off);
    }
    const float m = s * (1.0f / 512.0f);
    float var = sq * (1.0f / 512.0f) - m * m;
    var = fmaxf(var, 0.0f);
    const float rs = rsqrtf(var + 1e-5f);
#pragma unroll
    for (int i = 0; i < 8; ++i)
        u[i] = f2bf((f[i] - m) * rs * b2f(g[c8 + i]) + b2f(b[c8 + i]));
    *(uint4*)p = v;
}

__global__ void zero_f32(float* __restrict__ p, int n)
{
    const int i = blockIdx.x * 256 + threadIdx.x;
    if (i < n) p[i] = 0.0f;
}

// Column sum-of-squares over n of ws-bf16 (B,4096,512), chunked + atomic
__global__ void colssq(const u16* __restrict__ in, float* __restrict__ ssq, int rowsPerChunk)
{
    const int b = blockIdx.x, cchunk = blockIdx.y, nchunk = blockIdx.z;
    const int c = cchunk * 256 + threadIdx.x;
    const u16* p = in + (long)b * 4096 * 512 + (long)nchunk * rowsPerChunk * 512 + c;
    float acc = 0.f;
    for (int n = 0; n < rowsPerChunk; ++n) {
        const float v = b2f(p[(long)n * 512]);
        acc += v * v;
    }
    atomicAdd(&ssq[b * 512 + c], acc);
}

// Row softmax over 512 (1/sqrt(512) pre-scale), f32 partials in -> bf16 out
__global__ void softmax_ab(const float* __restrict__ Ab, u16* __restrict__ out,
                           long sstride, int nsplit)
{
    const long row = blockIdx.x;
    const float* p = Ab + row * 512;
    const int tid = threadIdx.x;
    const float scale = 0.044194173824159216f;  // 1/sqrt(512)
    float a = 0.f, b = 0.f;
    for (int s = 0; s < nsplit; ++s) {
        a += p[(long)s * sstride + tid];
        b += p[(long)s * sstride + tid + 256];
    }
    a *= scale; b *= scale;
    float m = fmaxf(a, b);
#pragma unroll
    for (int off = 32; off > 0; off >>= 1) m = fmaxf(m, __shfl_xor(m, off));
    __shared__ float red[8];
    if ((tid & 63) == 0) red[tid >> 6] = m;
    __syncthreads();
    m = fmaxf(fmaxf(red[0], red[1]), fmaxf(red[2], red[3]));
    const float e0 = __expf(a - m), e1 = __expf(b - m);
    float s = e0 + e1;
#pragma unroll
    for (int off = 32; off > 0; off >>= 1) s += __shfl_xor(s, off);
    if ((tid & 63) == 0) red[4 + (tid >> 6)] = s;
    __syncthreads();
    s = red[4] + red[5] + red[6] + red[7];
    const float inv = 1.0f / fmaxf(s, 1e-30f);
    out[row * 512 + tid]       = f2bf(e0 * inv);
    out[row * 512 + tid + 256] = f2bf(e1 * inv);
}

// Row softmax over 64; logits = G[d][e]*rescale[h]/(||k_d||*||q_e||). Row=z*64+d.
// G comes as nsplit f32 partial buffers (K-split gemm), summed here.
__global__ void softmax_g(const float* __restrict__ G, const u16* __restrict__ rescale,
                          const float* __restrict__ ssq_k, const float* __restrict__ ssq_q,
                          u16* __restrict__ out, long sstride, int nsplit)
{
    const int row = blockIdx.x * 4 + (threadIdx.x >> 6);
    const int lane = threadIdx.x & 63;
    const int zz = row >> 6, d = row & 63;
    const int b_ = zz >> 3, h = zz & 7;
    const float rk = 1.0f / fmaxf(sqrtf(fmaxf(ssq_k[b_ * 512 + h * 64 + d], 0.f)), 1e-12f);
    const float rq = 1.0f / fmaxf(sqrtf(fmaxf(ssq_q[b_ * 512 + h * 64 + lane], 0.f)), 1e-12f);
    float gv = 0.f;
    for (int s = 0; s < nsplit; ++s)
        gv += G[(long)s * sstride + (long)row * 64 + lane];
    const float v = gv * rk * rq * b2f(rescale[h]);
    float m = v;
#pragma unroll
    for (int off = 32; off > 0; off >>= 1) m = fmaxf(m, __shfl_xor(m, off));
    const float e = __expf(v - m);
    float s = e;
#pragma unroll
    for (int off = 32; off > 0; off >>= 1) s += __shfl_xor(s, off);
    out[(long)row * 64 + lane] = f2bf(e / fmaxf(s, 1e-30f));
}

// Depthwise 3x3 SAME conv on NHWC (B,64,64,512) ws bf16, optional exact GeLU.
__global__ void dwconv3x3(const u16* __restrict__ in, const u16* __restrict__ w,
                          u16* __restrict__ out, int do_gelu)
{
    __shared__ u16 wl[4608];
    const int tid = threadIdx.x;
    for (int i = tid; i < 4608; i += 256) wl[i] = w[i];
    __syncthreads();
    const int b = blockIdx.x >> 6, y = blockIdx.x & 63;
    const long base = (long)b * 64 * 64 * 512;
    for (int t = 0; t < 16; ++t) {
        const int idx = t * 256 + tid;
        const int cg = idx & 63, x = idx >> 6;
        float acc[8] = {};
#pragma unroll
        for (int dy = -1; dy <= 1; ++dy) {
            const int yy = y + dy;
            if (yy < 0 || yy > 63) continue;
#pragma unroll
            for (int dx = -1; dx <= 1; ++dx) {
                const int xx = x + dx;
                if (xx < 0 || xx > 63) continue;
                const uint4 v = *(const uint4*)(in + base + ((long)yy * 64 + xx) * 512 + cg * 8);
                const u16* u = (const u16*)&v;
                const int wo = (dy + 1) * 3 + (dx + 1);
#pragma unroll
                for (int i = 0; i < 8; ++i)
                    acc[i] += b2f(u[i]) * b2f(wl[(cg * 8 + i) * 9 + wo]);
            }
        }
        u16 res[8];
#pragma unroll
        for (int i = 0; i < 8; ++i) {
            float v = acc[i];
            if (do_gelu) v = 0.5f * v * (1.0f + erff(v * 0.70710678118654752f));
            res[i] = f2bf(v);
        }
        *(uint4*)(out + base + ((long)y * 64 + x) * 512 + cg * 8) = *(uint4*)res;
    }
}

// ---------------------------------------------------------------------------
extern "C" void kernel_launch(void* const* d_in, const int* in_sizes, int n_in,
                              void* d_out, int out_size, void* d_ws, size_t ws_size,
                              hipStream_t stream)
{
    const void* x     = d_in[0];
    const void* illu  = d_in[1];
    const void* sem   = d_in[2];
    const void* WkS   = d_in[3];
    const void* WqS   = d_in[4];
    const void* WvS   = d_in[5];
    const void* ln_g  = d_in[6];
    const void* ln_b  = d_in[7];
    const void* Wq    = d_in[8];
    const void* Wk    = d_in[9];
    const void* Wv    = d_in[10];
    const void* resc  = d_in[11];
    const void* projW = d_in[12];
    const void* projB = d_in[13];
    const void* dw1   = d_in[14];
    const void* dw2   = d_in[15];
    (void)in_sizes; (void)n_in; (void)out_size; (void)ws_size;

    char* ws = (char*)d_ws;
    size_t off = 0;
    auto nxt = [&](size_t bytes) -> void* {
        void* p = ws + off;
        off += (bytes + 255) & ~(size_t)255;
        return p;
    };

    // Workspace ~119 MB
    u16* WqT   = (u16*)nxt(524288);
    u16* WkT   = (u16*)nxt(524288);
    u16* WvT   = (u16*)nxt(524288);
    u16* WkST  = (u16*)nxt(524288);
    u16* WqST  = (u16*)nxt(524288);
    u16* WvST  = (u16*)nxt(524288);
    u16* projT = (u16*)nxt(524288);
    u16* A = (u16*)nxt(33554432);   // 3 reusable 33.5MB slots
    u16* B = (u16*)nxt(33554432);
    u16* C = (u16*)nxt(33554432);
    float* Abf  = (float*)nxt(8388608);
    u16*   Absm = (u16*)nxt(4194304);
    float* mu   = (float*)nxt(131072);
    float* rs   = (float*)nxt(131072);
    float* ssq_q = (float*)nxt(16384);
    float* ssq_k = (float*)nxt(16384);
    float* Gf   = (float*)nxt(1048576);
    u16*   attn = (u16*)nxt(524288);
    int*   dflag = (int*)nxt(256);
    u16* ln_gc  = (u16*)nxt(1024);
    u16* ln_bc  = (u16*)nxt(1024);
    u16* projBc = (u16*)nxt(1024);
    u16* rescc  = (u16*)nxt(256);
    u16* dw1c   = (u16*)nxt(9216);
    u16* dw2c   = (u16*)nxt(9216);
    (void)Gf; (void)mu; (void)rs;

    const dim3 blk(256);

    // --- dtype detection + small-vector conversion -----------------------
    detect_dtype<<<dim3(1), blk, 0, stream>>>((const u16*)x, dflag);
    to_bf16<<<dim3(2), blk, 0, stream>>>(ln_g,  ln_gc,  512,  dflag);
    to_bf16<<<dim3(2), blk, 0, stream>>>(ln_b,  ln_bc,  512,  dflag);
    to_bf16<<<dim3(2), blk, 0, stream>>>(projB, projBc, 512,  dflag);
    to_bf16<<<dim3(1), blk, 0, stream>>>(resc,  rescc,  8,    dflag);
    to_bf16<<<dim3(18), blk, 0, stream>>>(dw1,  dw1c,   4608, dflag);
    to_bf16<<<dim3(18), blk, 0, stream>>>(dw2,  dw2c,   4608, dflag);

    auto wT = [&](const void* w, u16* o) {
        transpose_k<<<dim3(8, 8, 1), blk, 0, stream>>>(w, o, dflag);
    };
    wT(Wq, WqT); wT(Wk, WkT); wT(Wv, WvT);
    wT(WkS, WkST); wT(WqS, WqST); wT(WvS, WvST); wT(projW, projT);

    // fast bf16 GEMM (exact multiples of tile)
    auto gemmf = [&](const u16* Ap, const u16* Btp, void* Cp, int M, int N, int K,
                     int lda, int ldb, int ldc, int nz, int nh,
                     long sAb, long sAh, long sBb, long sBh, long sCb, long sCh,
                     int epi, const u16* add1, long sAddB, long sAddH, int ldadd,
                     const u16* mul1, const u16* bias, const int* cF32) {
        dim3 g(M / 128, N / 128, nz);
        gemm_btf<<<g, blk, 0, stream>>>(Ap, Btp, Cp, M, N, K, lda, ldb, ldc,
            sAb, sAh, sBb, sBh, sCb, sCh, nh, epi, add1, sAddB, sAddH, ldadd,
            mul1, bias, cF32);
    };

    // --- SIF channel attention -------------------------------------------
    // illub -> C (first use)
    to_bf16_v8<<<dim3(8192), blk, 0, stream>>>(illu, C, 2097152, dflag);
    gemmf(C, WkST, A, 32768, 512, 512, 512, 512, 512, 1, 1, 0,0,0,0,0,0, 1,
          nullptr,0,0,0, nullptr, nullptr, nullptr);          // Kn -> A
    ln_fused<<<dim3(8192), blk, 0, stream>>>(A, ln_gc, ln_bc);
    // semb -> C (illub dead)
    to_bf16_v8<<<dim3(8192), blk, 0, stream>>>(sem, C, 2097152, dflag);
    gemmf(C, WqST, B, 32768, 512, 512, 512, 512, 512, 1, 1, 0,0,0,0,0,0, 1,
          nullptr,0,0,0, nullptr, nullptr, nullptr);          // Qn -> B
    ln_fused<<<dim3(8192), blk, 0, stream>>>(B, ln_gc, ln_bc);
    // Ab partials (K-split x4) -> C (f32; semb dead)
    float* Cf = (float*)C;
    gemm_at<<<dim3(4, 4, 32), blk, 0, stream>>>(B, A, Cf, 512, 512, 1024,
        512, 512, 512, 524288, 2097152, 524288, 2097152, 2097152, 262144, 8);
    softmax_ab<<<dim3(4096), blk, 0, stream>>>(Cf, Absm, 2097152, 4);

    // --- q/k paths + head attention matrix -------------------------------
    u16* xb = C;  // xb -> C (partials dead)
    to_bf16_v8<<<dim3(8192), blk, 0, stream>>>(x, xb, 2097152, dflag);
    gemmf(xb, WqT, A, 32768, 512, 512, 512, 512, 512, 1, 1, 0,0,0,0,0,0, 1,
          nullptr,0,0,0, nullptr, nullptr, nullptr);          // q -> A
    zero_f32<<<dim3(16), blk, 0, stream>>>(ssq_q, 4096);
    colssq<<<dim3(8, 2, 16), blk, 0, stream>>>(A, ssq_q, 256);
    gemmf(xb, WkT, B, 32768, 512, 512, 512, 512, 512, 1, 1, 0,0,0,0,0,0, 1,
          nullptr,0,0,0, nullptr, nullptr, nullptr);          // k -> B
    zero_f32<<<dim3(16), blk, 0, stream>>>(ssq_k, 4096);
    colssq<<<dim3(8, 2, 16), blk, 0, stream>>>(B, ssq_k, 256);
    // G partials (K-split x8) -> Abf
    gemm_at<<<dim3(1, 1, 512), blk, 0, stream>>>(B, A, Abf, 64, 64, 512,
        512, 512, 64, 262144, 64, 262144, 64, 262144, 4096, 64);
    softmax_g<<<dim3(1024), blk, 0, stream>>>(Abf, rescc, ssq_k, ssq_q, attn,
        262144, 8);

    // --- v path + output --------------------------------------------------
    gemmf(xb, WvT, A, 32768, 512, 512, 512, 512, 512, 1, 1, 0,0,0,0,0,0, 1,
          nullptr,0,0,0, nullptr, nullptr, nullptr);          // v -> A (q dead)
    // illub again -> C (xb dead)
    to_bf16_v8<<<dim3(8192), blk, 0, stream>>>(illu, C, 2097152, dflag);
    gemmf(C, WvST, B, 32768, 512, 512, 512, 512, 512, 1, 1, 0,0,0,0,0,0, 1,
          nullptr,0,0,0, nullptr, nullptr, nullptr);          // vsif -> B (k dead)
    // vg = (vsif@Absm^T + vsif) * v -> C (illub dead)
    gemmf(B, Absm, C, 4096, 512, 512, 512, 512, 512, 8, 1,
          2097152, 0, 262144, 0, 2097152, 0, 2, B, 2097152, 0, 512, A, nullptr,
          nullptr);
    // o[b][n][h*64+d] = sum_e attn[z][d][e]*vg[b][n][h*64+e] -> B (guarded kernel)
    gemm_bt<<<dim3(32, 1, 64), blk, 0, stream>>>(C, attn, B, 4096, 64, 64,
        512, 64, 512, 2097152, 64, 32768, 4096, 2097152, 64, 8,
        1, nullptr, 0, 0, 0, nullptr, nullptr, nullptr, nullptr);
    // positional: p1 = gelu(dw(v)) -> C ; p2 = dw(p1) -> A
    dwconv3x3<<<dim3(512), blk, 0, stream>>>(A, dw1c, C, 1);
    dwconv3x3<<<dim3(512), blk, 0, stream>>>(C, dw2c, A, 0);
    // out = o@proj_w + proj_b + p2 -> d_out (width per dflag)
    gemmf(B, projT, d_out, 32768, 512, 512, 512, 512, 512, 1, 1, 0,0,0,0,0,0,
          3, A, 0, 0, 512, nullptr, projBc, dflag);
}